// Round 1
// baseline (283.369 us; speedup 1.0000x reference)
//
#include <hip/hip_runtime.h>

// Fixed shapes from the reference: B=64, C=64, H=96, W=96 (Q10 fixed point).
#define B_   64
#define C_   64
#define HW_  9216                      // 96*96
#define NSLAB (B_ * C_)                // 4096 contiguous [b][c] slabs of HW_ ints
#define M_   ((long long)B_ * HW_)     // 589824 elements per channel
#define FX_ONE_SQRT 32

typedef int v4i __attribute__((ext_vector_type(4)));

// ---------------- Kernel 1: per-slab sum / sum-of-squares ----------------
// Pure 32-bit per-thread accumulation: 36 elems/thread, max sum 36*2047 < 2^17,
// max sumsq 36*2047^2 = 1.51e8 < 2^31. Widen to 64-bit only at the wave reduce.
// HBM-bound: 144 MiB read -> ~24 us floor. Left unchanged.
__global__ __launch_bounds__(256) void k_reduce(const int* __restrict__ x,
                                                long long* __restrict__ part) {
    const int slab = blockIdx.x;                          // slab = b*C + c
    const v4i* p = (const v4i*)(x + (size_t)slab * HW_);
    unsigned tsum = 0, tsq = 0;
#pragma unroll
    for (int i = 0; i < HW_ / 4 / 256; ++i) {             // 9 int4 per thread
        v4i v = p[threadIdx.x + i * 256];
        tsum += (unsigned)(v.x + v.y + v.z + v.w);
        tsq  += (unsigned)(v.x * v.x) + (unsigned)(v.y * v.y)
              + (unsigned)(v.z * v.z) + (unsigned)(v.w * v.w);
    }
    long long s = tsum, q = tsq;
#pragma unroll
    for (int off = 32; off > 0; off >>= 1) {              // wave64 reduce
        s += __shfl_down(s, off, 64);
        q += __shfl_down(q, off, 64);
    }
    __shared__ long long ss[4], sq[4];
    const int wave = threadIdx.x >> 6, lane = threadIdx.x & 63;
    if (lane == 0) { ss[wave] = s; sq[wave] = q; }
    __syncthreads();
    if (threadIdx.x == 0) {
        part[2 * slab]     = ss[0] + ss[1] + ss[2] + ss[3];
        part[2 * slab + 1] = sq[0] + sq[1] + sq[2] + sq[3];
    }
}

// ---------------- Kernel 2: fused params + normalize ----------------
// Each block redundantly computes its own channel's params from the 64
// per-batch partials (deterministic -> all 64 blocks of a channel agree):
//  - mean: round-to-nearest (ref: floor + Bernoulli; |diff| <= 1)
//  - var:  round-to-nearest of exact centered sumsq / (1024*M)
//  - isqrt: exact bit-serial (ref's internal fx_div(r,2) always has mod==0)
//
// Final fx_div replaced by ONE f32 FMA per element:
//   y = round_ne( x*s + t ),  s = fl32(gamma/den),  t = fl32(beta - mean*(double)s)
// t is computed against the FLOAT s, so the mean term cancels exactly; total
// f32 error < 2e-3 << 0.5 (|x-mean| <= 2048, |s| ~ 1.7 for these inputs), so
// the rounded result always lands in {floor(a/den), floor(a/den)+1} -- the
// exact candidate set of the reference's floor+Bernoulli (threshold is 36.48).
// This removes the i64 muls / f64 divide-estimate / 3-branch fixup (~20+ VALU
// slots/elem, incl. half-rate f64) -> 4 VALU slots/elem. k_norm should become
// write-BW / L3-read bound.
__global__ __launch_bounds__(256) void k_norm(const int* __restrict__ x,
                                              int* __restrict__ y,
                                              const long long* __restrict__ part,
                                              const int* __restrict__ gammap,
                                              const int* __restrict__ betap,
                                              const int* __restrict__ mov_mean,
                                              const int* __restrict__ mov_std,
                                              const int* __restrict__ is_t_p) {
    __shared__ float sh_s, sh_t;
    const int slab = blockIdx.x;
    const int c = slab & (C_ - 1);

    if (threadIdx.x < 64) {                               // wave 0: channel params
        const int b = threadIdx.x;
        long long s = part[2 * (b * C_ + c)];
        long long q = part[2 * (b * C_ + c) + 1];
#pragma unroll
        for (int off = 32; off > 0; off >>= 1) {
            s += __shfl_down(s, off, 64);
            q += __shfl_down(q, off, 64);
        }
        if (b == 0) {
            int mean, den;
            if (is_t_p[0]) {
                mean = (int)((s + M_ / 2) / M_);
                long long sc = q - 2LL * mean * s + M_ * (long long)mean * mean;
                long long d2 = M_ * 1024LL;
                long long var = (sc + d2 / 2) / d2;
                long long v = var + 1;                    // + EPS_FX
                long long r = 0, a = 1LL << 30;           // bit-serial isqrt
                while (a) {
                    if (r + a <= v) { v -= r + a; r = (r >> 1) + a; }
                    else            { r >>= 1; }
                    a >>= 2;
                }
                den = (int)(r * FX_ONE_SQRT);
            } else {
                mean = mov_mean[c];
                den  = mov_std[c];
            }
            const float sf = (float)((double)gammap[c] / (double)den);
            sh_s = sf;
            // exact in double: mean*(double)sf has <= 35 significant bits
            sh_t = (float)((double)betap[c] - (double)mean * (double)sf);
        }
    }
    __syncthreads();
    const float sc = sh_s, tc = sh_t;

    const v4i* xp = (const v4i*)(x + (size_t)slab * HW_);
    v4i*       yp = (v4i*)(y + (size_t)slab * HW_);
#pragma unroll
    for (int i = 0; i < HW_ / 4 / 256; ++i) {
        v4i v = xp[threadIdx.x + i * 256];
        v4i o;
#pragma unroll
        for (int j = 0; j < 4; ++j) {
            o[j] = __float2int_rn(fmaf((float)v[j], sc, tc));
        }
        // Non-temporal: keep y out of L3 so x stays resident for the reads.
        __builtin_nontemporal_store(o, &yp[threadIdx.x + i * 256]);
    }
}

extern "C" void kernel_launch(void* const* d_in, const int* in_sizes, int n_in,
                              void* d_out, int out_size, void* d_ws, size_t ws_size,
                              hipStream_t stream) {
    const int* x        = (const int*)d_in[0];
    const int* gamma    = (const int*)d_in[1];
    const int* beta     = (const int*)d_in[2];
    const int* mov_mean = (const int*)d_in[3];
    const int* mov_std  = (const int*)d_in[4];
    const int* is_t     = (const int*)d_in[5];
    int* y = (int*)d_out;

    long long* part = (long long*)d_ws;                   // 4096*2 int64 = 64 KB

    k_reduce<<<NSLAB, 256, 0, stream>>>(x, part);
    k_norm<<<NSLAB, 256, 0, stream>>>(x, y, part, gamma, beta,
                                      mov_mean, mov_std, is_t);
}